// Round 2
// baseline (395.300 us; speedup 1.0000x reference)
//
#include <hip/hip_runtime.h>

#define HH 64
#define WW 64
#define HWC 4096   // H*W
#define LATENT 128

__global__ __launch_bounds__(256)
void oracle_kernel(const float4* __restrict__ x,
                   const float* __restrict__ proj,
                   float* __restrict__ out,
                   int B) {
    const int b    = blockIdx.x;
    const int tid  = threadIdx.x;
    const int lane = tid & 63;
    const int wave = tid >> 6;

    const float4* xb = x + (size_t)b * HWC;

    // ---- Pass 1: load all 4096 cells (16 per thread), build food mask,
    //      food count, and min opponent index ----
    unsigned fmask = 0u;
    int cnt = 0;
    int minopp = HWC;   // sentinel: "no opponent"
#pragma unroll
    for (int k = 0; k < 16; ++k) {
        const int idx = k * 256 + tid;
        const float4 v = xb[idx];
        if (v.y == 1.0f) { fmask |= (1u << k); ++cnt; }
        if (v.w == 1.0f && idx < minopp) minopp = idx;  // k ascending -> first hit wins
    }

    // wave-level reduce (64 lanes)
#pragma unroll
    for (int off = 32; off >= 1; off >>= 1) {
        minopp = min(minopp, __shfl_down(minopp, off, 64));
        cnt   += __shfl_down(cnt, off, 64);
    }

    __shared__ int s_opp[4], s_cnt[4], s_key[4];
    if (lane == 0) { s_opp[wave] = minopp; s_cnt[wave] = cnt; }
    __syncthreads();

    int opp_all = HWC, cnt_all = 0;
#pragma unroll
    for (int i = 0; i < 4; ++i) { opp_all = min(opp_all, s_opp[i]); cnt_all += s_cnt[i]; }

    // jnp.argmax over all-False returns 0
    const int opp_flat = (opp_all < HWC) ? opp_all : 0;
    const int orow = opp_flat >> 6;
    const int ocol = opp_flat & 63;

    // ---- Pass 2: argmin of distance over food cells, first-min tie-break ----
    // key = (d2 << 12) | idx : min(key) == (min d2, then min idx).
    // d2 <= 2*63*63 = 7938, so key < 2^25 — no overflow.
    int key = 0x7fffffff;
#pragma unroll
    for (int k = 0; k < 16; ++k) {
        if (fmask & (1u << k)) {
            const int idx = k * 256 + tid;
            const int di = (idx >> 6) - orow;
            const int dj = (idx & 63) - ocol;
            const int d2 = di * di + dj * dj;
            key = min(key, (d2 << 12) | idx);
        }
    }
#pragma unroll
    for (int off = 32; off >= 1; off >>= 1) {
        key = min(key, __shfl_down(key, off, 64));
    }
    if (lane == 0) s_key[wave] = key;
    __syncthreads();

    int key_all = 0x7fffffff;
#pragma unroll
    for (int i = 0; i < 4; ++i) key_all = min(key_all, s_key[i]);

    const int target_row = (key_all & (HWC - 1)) >> 6;
    const float is_top = (target_row < (HH / 2)) ? 1.0f : -1.0f;
    const bool opp_at_start = (opp_flat == 3 * WW + 6);

    float s;
    if (cnt_all > 1 && !opp_at_start) s = is_top;
    else if (cnt_all == 1)            s = is_top;
    else                              s = 0.0f;

    // ---- Epilogue: g = s * projector ; second output is zeros ----
    if (tid < LATENT) {
        const size_t o = (size_t)b * LATENT + tid;
        out[o] = s * proj[tid];
        out[(size_t)B * LATENT + o] = 0.0f;
    }
}

extern "C" void kernel_launch(void* const* d_in, const int* in_sizes, int n_in,
                              void* d_out, int out_size, void* d_ws, size_t ws_size,
                              hipStream_t stream) {
    const float* x    = (const float*)d_in[0];
    const float* proj = (const float*)d_in[1];
    float* out = (float*)d_out;
    const int B = in_sizes[0] / (HWC * 4);   // (B, 64, 64, 4) float32
    // MEASUREMENT ROUND: launch the identical kernel twice, back-to-back.
    // Same-stream serialization means dur_us_new - dur_us_old == one kernel
    // duration K, which is hidden below the 160 us harness fills in rocprof
    // top-5. Decides roofline-vs-headroom next round.
    oracle_kernel<<<B, 256, 0, stream>>>((const float4*)x, proj, out, B);
    oracle_kernel<<<B, 256, 0, stream>>>((const float4*)x, proj, out, B);
}

// Round 3
// 357.359 us; speedup vs baseline: 1.1062x; 1.1062x over previous
//
#include <hip/hip_runtime.h>

#define HH 64
#define WW 64
#define HWC 4096   // H*W
#define LATENT 128

// Memory-bound at HBM roofline. Measured via double-launch A/B (R1 vs R2):
// marginal kernel cost = 395.3 - 357.5 = 37.8 us vs ~40.7 us floor for
// 256 MiB read + 4 MiB write at 6.7 TB/s achieved BW. Traffic is
// irreducible: channels 1 & 3 interleave at 16 B stride, so every input
// cache line must be fetched.
__global__ __launch_bounds__(256)
void oracle_kernel(const float4* __restrict__ x,
                   const float* __restrict__ proj,
                   float* __restrict__ out,
                   int B) {
    const int b    = blockIdx.x;
    const int tid  = threadIdx.x;
    const int lane = tid & 63;
    const int wave = tid >> 6;

    const float4* xb = x + (size_t)b * HWC;

    // ---- Pass 1: load all 4096 cells (16 per thread), build food mask,
    //      food count, and min opponent index ----
    unsigned fmask = 0u;
    int cnt = 0;
    int minopp = HWC;   // sentinel: "no opponent"
#pragma unroll
    for (int k = 0; k < 16; ++k) {
        const int idx = k * 256 + tid;
        const float4 v = xb[idx];
        if (v.y == 1.0f) { fmask |= (1u << k); ++cnt; }
        if (v.w == 1.0f && idx < minopp) minopp = idx;  // k ascending -> first hit wins
    }

    // wave-level reduce (64 lanes)
#pragma unroll
    for (int off = 32; off >= 1; off >>= 1) {
        minopp = min(minopp, __shfl_down(minopp, off, 64));
        cnt   += __shfl_down(cnt, off, 64);
    }

    __shared__ int s_opp[4], s_cnt[4], s_key[4];
    if (lane == 0) { s_opp[wave] = minopp; s_cnt[wave] = cnt; }
    __syncthreads();

    int opp_all = HWC, cnt_all = 0;
#pragma unroll
    for (int i = 0; i < 4; ++i) { opp_all = min(opp_all, s_opp[i]); cnt_all += s_cnt[i]; }

    // jnp.argmax over all-False returns 0
    const int opp_flat = (opp_all < HWC) ? opp_all : 0;
    const int orow = opp_flat >> 6;
    const int ocol = opp_flat & 63;

    // ---- Pass 2: argmin of distance over food cells, first-min tie-break ----
    // key = (d2 << 12) | idx : min(key) == (min d2, then min idx).
    // d2 <= 2*63*63 = 7938, so key < 2^25 — no overflow. Integer d2 argmin is
    // exactly equivalent to fp32 sqrt argmin (sqrt monotone, distinct d2 ->
    // distinct fp32 values at this range).
    int key = 0x7fffffff;
#pragma unroll
    for (int k = 0; k < 16; ++k) {
        if (fmask & (1u << k)) {
            const int idx = k * 256 + tid;
            const int di = (idx >> 6) - orow;
            const int dj = (idx & 63) - ocol;
            const int d2 = di * di + dj * dj;
            key = min(key, (d2 << 12) | idx);
        }
    }
#pragma unroll
    for (int off = 32; off >= 1; off >>= 1) {
        key = min(key, __shfl_down(key, off, 64));
    }
    if (lane == 0) s_key[wave] = key;
    __syncthreads();

    int key_all = 0x7fffffff;
#pragma unroll
    for (int i = 0; i < 4; ++i) key_all = min(key_all, s_key[i]);

    const int target_row = (key_all & (HWC - 1)) >> 6;
    const float is_top = (target_row < (HH / 2)) ? 1.0f : -1.0f;
    const bool opp_at_start = (opp_flat == 3 * WW + 6);

    float s;
    if (cnt_all > 1 && !opp_at_start) s = is_top;
    else if (cnt_all == 1)            s = is_top;
    else                              s = 0.0f;

    // ---- Epilogue: g = s * projector ; second output is zeros ----
    if (tid < LATENT) {
        const size_t o = (size_t)b * LATENT + tid;
        out[o] = s * proj[tid];
        out[(size_t)B * LATENT + o] = 0.0f;
    }
}

extern "C" void kernel_launch(void* const* d_in, const int* in_sizes, int n_in,
                              void* d_out, int out_size, void* d_ws, size_t ws_size,
                              hipStream_t stream) {
    const float* x    = (const float*)d_in[0];
    const float* proj = (const float*)d_in[1];
    float* out = (float*)d_out;
    const int B = in_sizes[0] / (HWC * 4);   // (B, 64, 64, 4) float32
    oracle_kernel<<<B, 256, 0, stream>>>((const float4*)x, proj, out, B);
}